// Round 7
// baseline (16337.561 us; speedup 1.0000x reference)
//
#include <hip/hip_runtime.h>

// Decoder ODE-RNN (GRU + Euler-2 ODE + softmax emit). Inputs/outputs FLOAT32.
// f32 GEMM emulated via bf16x3 splitting (6 MFMAs: hh+hm+mh+mm+hl+lh).
// R7 change vs R6 (14.1ms, passed, FETCH 6.6GB == R4 -> acquire-invalidate
// still forced full weight+activation refetch from L3 every phase):
//   - barrier: RELEASE-only arrive RMW (waitcnt+wbl2: flushes dirty activation
//     lines, does NOT invalidate clean weight lines) + RELAXED polls; NO
//     acquire anywhere -> weights stay resident in each XCD's L2 across steps.
//   - cross-block activation READS use agent-scope RELAXED atomic loads
//     (8B pairs for bf16x8 fragments, 4B scalars) which bypass stale L1/L2
//     and read the L3 coherent point. R6 proved these see remote writes.
//   - weights/data/biases keep normal cached loads (immutable).
// Numerics bit-identical to R6/R4/R1 (absmax 1.0).

typedef __bf16 bf16_t;
typedef __bf16 bf16x8 __attribute__((ext_vector_type(8)));
typedef float  f32x4  __attribute__((ext_vector_type(4)));

#define BM 64
#define BN 64
#define BK 64
#define LDT 72    // padded LDS row stride
#define NBLK 256  // 1 block/CU

__device__ __forceinline__ float sigmoidf_(float x) { return 1.f / (1.f + expf(-x)); }

__device__ __forceinline__ void split3(float v, bf16_t& h, bf16_t& m, bf16_t& l) {
  h = (bf16_t)v; float r1 = v - (float)h;
  m = (bf16_t)r1; float r2 = r1 - (float)m;
  l = (bf16_t)r2;
}

#define CHAIN6(c, ah, am, al, bh, bm, bl) \
  c = __builtin_amdgcn_mfma_f32_16x16x32_bf16(ah, bh, c, 0, 0, 0); \
  c = __builtin_amdgcn_mfma_f32_16x16x32_bf16(ah, bm, c, 0, 0, 0); \
  c = __builtin_amdgcn_mfma_f32_16x16x32_bf16(am, bh, c, 0, 0, 0); \
  c = __builtin_amdgcn_mfma_f32_16x16x32_bf16(am, bm, c, 0, 0, 0); \
  c = __builtin_amdgcn_mfma_f32_16x16x32_bf16(ah, bl, c, 0, 0, 0); \
  c = __builtin_amdgcn_mfma_f32_16x16x32_bf16(al, bh, c, 0, 0, 0);

// ---------------- coherent (L2-bypassing, agent-scope) activation loads
__device__ __forceinline__ bf16x8 ld8c(const bf16_t* p) {
  union { unsigned long long u[2]; bf16x8 v; } r;
  const unsigned long long* q = (const unsigned long long*)p;
  r.u[0] = __hip_atomic_load(q,     __ATOMIC_RELAXED, __HIP_MEMORY_SCOPE_AGENT);
  r.u[1] = __hip_atomic_load(q + 1, __ATOMIC_RELAXED, __HIP_MEMORY_SCOPE_AGENT);
  return r.v;
}
__device__ __forceinline__ float ldfc(const float* p) {
  return __hip_atomic_load(p, __ATOMIC_RELAXED, __HIP_MEMORY_SCOPE_AGENT);
}

// flag-aware loads from HARNESS inputs (f32 vs bf16 decided at runtime)
__device__ __forceinline__ void loadf8(const void* p, size_t idx, int isf32, float out[8]) {
  if (isf32) {
    const float* q = (const float*)p + idx;
    f32x4 a = *(const f32x4*)q;
    f32x4 b = *(const f32x4*)(q + 4);
    out[0]=a[0]; out[1]=a[1]; out[2]=a[2]; out[3]=a[3];
    out[4]=b[0]; out[5]=b[1]; out[6]=b[2]; out[7]=b[3];
  } else {
    bf16x8 v = *(const bf16x8*)((const bf16_t*)p + idx);
#pragma unroll
    for (int i = 0; i < 8; i++) out[i] = (float)v[i];
  }
}
__device__ __forceinline__ float loadf(const void* p, int idx, int isf32) {
  return isf32 ? ((const float*)p)[idx] : (float)((const bf16_t*)p)[idx];
}

__global__ void k_probe(const unsigned int* ts_raw, int* flag) {
  *flag = (ts_raw[0] == 0u) ? 1 : 0;   // 1 = f32 inputs, 0 = bf16 inputs
}

// ---------------- grid-wide barrier (sense-reversing, agent scope).
// bar[0] = arrive count, bar[32] = generation (128B apart).
// Arrive = RELEASE RMW (flush own writes to L3, no invalidate).
// Wait = RELAXED polls; NO acquire (readers use ld8c/ldfc coherent loads).
__device__ __forceinline__ void gbar(int* bar) {
  __syncthreads();
  if (threadIdx.x == 0) {
    int g = __hip_atomic_load(bar + 32, __ATOMIC_RELAXED, __HIP_MEMORY_SCOPE_AGENT);
    int old = __hip_atomic_fetch_add(bar, 1, __ATOMIC_RELEASE, __HIP_MEMORY_SCOPE_AGENT);
    if (old == NBLK - 1) {
      __hip_atomic_store(bar, 0, __ATOMIC_RELAXED, __HIP_MEMORY_SCOPE_AGENT);
      __hip_atomic_fetch_add(bar + 32, 1, __ATOMIC_RELEASE, __HIP_MEMORY_SCOPE_AGENT);
    } else {
      while (__hip_atomic_load(bar + 32, __ATOMIC_RELAXED, __HIP_MEMORY_SCOPE_AGENT) == g) {
        __builtin_amdgcn_s_sleep(8);
      }
    }
  }
  __syncthreads();
}

// ---------------- split-precision GEMM core: C[64x64] tile (R1-proven).
// A planes are ACTIVATIONS -> coherent ld8c loads. B planes are WEIGHTS
// (immutable) -> normal cached loads. CATX x-part reads harness data (normal).
template<bool CATX>
__device__ __forceinline__ void gemm6_dev(
    bf16_t* __restrict__ AsB, bf16_t* __restrict__ BsB,
    const bf16_t* __restrict__ Ah, const bf16_t* __restrict__ Am, const bf16_t* __restrict__ Al,
    int lda,
    const void* __restrict__ X, int isf32, int t,
    const bf16_t* __restrict__ Bh, const bf16_t* __restrict__ Bm, const bf16_t* __restrict__ Bl,
    int K, int mBase, int nBase,
    f32x4 acc[2][2])
{
  const int tid  = threadIdx.x;
  const int srow = tid >> 2;
  const int sc   = (tid & 3) << 4;
  const int arow = mBase + srow;
  const int brow = nBase + srow;

  const int lane = tid & 63;
  const int wid  = tid >> 6;
  const int wm   = (wid & 1) * 32;
  const int wn   = (wid >> 1) * 32;
  const int q8   = (lane >> 4) << 3;
  const int l16  = lane & 15;

  f32x4 z = {0.f, 0.f, 0.f, 0.f};
#pragma unroll
  for (int i = 0; i < 2; i++)
#pragma unroll
    for (int j = 0; j < 2; j++) acc[i][j] = z;

  bf16x8 pA[3][2], pB[3][2];

  auto loadA = [&](int k0) {
    int gk = k0 + sc;
    if (CATX && gk >= 1024) {
      size_t off = (size_t)arow * 32768 + (size_t)t * 512 + (size_t)(gk - 1024);
      float v[16];
      loadf8(X, off,     isf32, v);
      loadf8(X, off + 8, isf32, v + 8);
#pragma unroll
      for (int u8 = 0; u8 < 2; u8++)
#pragma unroll
        for (int j = 0; j < 8; j++) {
          bf16_t h, m, l; split3(v[u8 * 8 + j], h, m, l);
          pA[0][u8][j] = h; pA[1][u8][j] = m; pA[2][u8][j] = l;
        }
    } else {
      size_t off = (size_t)arow * lda + gk;
      pA[0][0] = ld8c(Ah + off); pA[0][1] = ld8c(Ah + off + 8);
      pA[1][0] = ld8c(Am + off); pA[1][1] = ld8c(Am + off + 8);
      pA[2][0] = ld8c(Al + off); pA[2][1] = ld8c(Al + off + 8);
    }
  };
  auto loadB = [&](int k0) {
    size_t off = (size_t)brow * K + k0 + sc;
    pB[0][0] = *(const bf16x8*)(Bh + off); pB[0][1] = *(const bf16x8*)(Bh + off + 8);
    pB[1][0] = *(const bf16x8*)(Bm + off); pB[1][1] = *(const bf16x8*)(Bm + off + 8);
    pB[2][0] = *(const bf16x8*)(Bl + off); pB[2][1] = *(const bf16x8*)(Bl + off + 8);
  };

  loadA(0); loadB(0);

  for (int k0 = 0; k0 < K; k0 += BK) {
    const int wrow = srow * LDT + sc;
#pragma unroll
    for (int p = 0; p < 3; p++) {
      *(bf16x8*)&AsB[p * (BM * LDT) + wrow]     = pA[p][0];
      *(bf16x8*)&AsB[p * (BM * LDT) + wrow + 8] = pA[p][1];
      *(bf16x8*)&BsB[p * (BN * LDT) + wrow]     = pB[p][0];
      *(bf16x8*)&BsB[p * (BN * LDT) + wrow + 8] = pB[p][1];
    }
    __syncthreads();

    if (k0 + BK < K) { loadA(k0 + BK); loadB(k0 + BK); }

#pragma unroll
    for (int kk = 0; kk < BK; kk += 32) {
      bf16x8 a[2][3], b[2][3];
#pragma unroll
      for (int p = 0; p < 3; p++) {
        a[0][p] = *(const bf16x8*)&AsB[p * (BM * LDT) + (wm +      l16) * LDT + kk + q8];
        a[1][p] = *(const bf16x8*)&AsB[p * (BM * LDT) + (wm + 16 + l16) * LDT + kk + q8];
        b[0][p] = *(const bf16x8*)&BsB[p * (BN * LDT) + (wn +      l16) * LDT + kk + q8];
        b[1][p] = *(const bf16x8*)&BsB[p * (BN * LDT) + (wn + 16 + l16) * LDT + kk + q8];
      }
#pragma unroll
      for (int mi = 0; mi < 2; mi++)
#pragma unroll
        for (int ni = 0; ni < 2; ni++) {
          f32x4 c = acc[mi][ni];
          CHAIN6(c, a[mi][0], a[mi][1], a[mi][2], b[ni][0], b[ni][1], b[ni][2]);
          acc[mi][ni] = c;
        }
    }
    __syncthreads();
  }
}

// ---------------- args for the persistent mega-kernel
struct KArgs {
  const void* data; const void* ts;
  const void* bu; const void* br; const void* bn;
  const void* b1; const void* b2; const void* be;
  const bf16_t *WurTh, *WurTm, *WurTl;
  const bf16_t *WnTh,  *WnTm,  *WnTl;
  const bf16_t *W1Th,  *W1Tm,  *W1Tl;
  const bf16_t *W2Th,  *W2Tm,  *W2Tl;
  const bf16_t *WeTh,  *WeTm,  *WeTl;
  float *P0f, *P1f, *P2f, *uf, *lg;
  bf16_t *P0h, *P0m, *P0l;
  bf16_t *P1h, *P1m, *P1l;
  bf16_t *P2h, *P2m, *P2l;
  bf16_t *HRh, *HRm, *HRl;
  bf16_t *Th,  *Tm,  *Tl;
  float *states, *probs;
  const int* flg;
  int* bar;
};

// ---------------- persistent kernel: entire 63-step loop, 256 blocks x 256 thr.
__global__ __launch_bounds__(256, 1) void k_mega(KArgs a)
{
  __shared__ __align__(16) bf16_t AsB[3 * BM * LDT];   // 27648 B
  __shared__ __align__(16) bf16_t BsB[3 * BN * LDT];   // 27648 B

  const int bid  = blockIdx.x;
  const int tid  = threadIdx.x;
  const int lane = tid & 63;
  const int wid  = tid >> 6;
  const int isf32 = *a.flg;

  // ---- emit tile (logits = h3 @ We + be), 32 tiles: 8M x 4N, K=1024
  auto emit_tile = [&]() {
    const int mt = bid >> 2, nt = bid & 3;
    f32x4 acc[2][2];
    gemm6_dev<false>(AsB, BsB, a.P0h, a.P0m, a.P0l, 1024, nullptr, 0, 0,
                     a.WeTh, a.WeTm, a.WeTl, 1024, mt * BM, nt * BN, acc);
    const int row0 = mt * BM + (wid & 1) * 32 + ((lane >> 4) << 2);
    const int col0 = nt * BN + (wid >> 1) * 32 + (lane & 15);
#pragma unroll
    for (int mi = 0; mi < 2; mi++)
#pragma unroll
      for (int ni = 0; ni < 2; ni++)
#pragma unroll
        for (int r = 0; r < 4; r++) {
          int m = row0 + mi * 16 + r;
          int n = col0 + ni * 16;
          a.lg[m * 256 + n] = acc[mi][ni][r] + loadf(a.be, n, isf32);
        }
  };

  // ---- softmax: 4 rows per block (sb in [0,128)), 256 threads = 1 col each
  auto softmax_rows = [&](int sb, int t) {
    float* red = (float*)AsB;   // block-local LDS scratch
#pragma unroll
    for (int rr = 0; rr < 4; ++rr) {
      int m = sb * 4 + rr;
      float v = ldfc(&a.lg[m * 256 + tid]);
      red[tid] = v;
      __syncthreads();
      for (int s = 128; s > 0; s >>= 1) {
        if (tid < s) red[tid] = fmaxf(red[tid], red[tid + s]);
        __syncthreads();
      }
      float mx = red[0];
      __syncthreads();
      float e = expf(v - mx);
      red[tid] = e;
      __syncthreads();
      for (int s = 128; s > 0; s >>= 1) {
        if (tid < s) red[tid] += red[tid + s];
        __syncthreads();
      }
      a.probs[((size_t)t * 512 + m) * 256 + tid] = e / red[0];
      __syncthreads();
    }
  };

  for (int t = 0; t < 63; ++t) {
    const float sdt = 0.5f * (loadf(a.ts, t + 1, isf32) - loadf(a.ts, t, isf32));

    // ======== phase 1: gates(t) [256 tiles] + emit(t-1) [32 tiles, bid<32] ====
    {
      const int mt = bid >> 5, nt = bid & 31;
      f32x4 acc[2][2];
      gemm6_dev<true>(AsB, BsB, a.P0h, a.P0m, a.P0l, 1024, a.data, isf32, t,
                      a.WurTh, a.WurTm, a.WurTl, 1536, mt * BM, nt * BN, acc);
      const int row0 = mt * BM + (wid & 1) * 32 + ((lane >> 4) << 2);
      const int col0 = nt * BN + (wid >> 1) * 32 + (lane & 15);
#pragma unroll
      for (int mi = 0; mi < 2; mi++)
#pragma unroll
        for (int ni = 0; ni < 2; ni++)
#pragma unroll
          for (int r = 0; r < 4; r++) {
            int m = row0 + mi * 16 + r;
            int n = col0 + ni * 16;
            float v = acc[mi][ni][r];
            if (n < 1024) {
              a.uf[m * 1024 + n] = sigmoidf_(v + loadf(a.bu, n, isf32));
            } else {
              int nn = n - 1024;
              float rr = sigmoidf_(v + loadf(a.br, nn, isf32));
              float hv = ldfc(&a.P0f[m * 1024 + nn]) * rr;
              bf16_t h, mm_, l; split3(hv, h, mm_, l);
              int idx = m * 1024 + nn;
              a.HRh[idx] = h; a.HRm[idx] = mm_; a.HRl[idx] = l;
            }
          }
      if (t > 0 && bid < 32) emit_tile();   // emit reads P0 (h_t) - read-only, same as gates
    }
    gbar(a.bar);

    // ======== phase 2: cand(t) [bid<128] + softmax(t-1) [bid>=128] ========
    if (bid < 128) {
      const int mt = bid >> 4, nt = bid & 15;
      f32x4 acc[2][2];
      gemm6_dev<true>(AsB, BsB, a.HRh, a.HRm, a.HRl, 1024, a.data, isf32, t,
                      a.WnTh, a.WnTm, a.WnTl, 1536, mt * BM, nt * BN, acc);
      const int row0 = mt * BM + (wid & 1) * 32 + ((lane >> 4) << 2);
      const int col0 = nt * BN + (wid >> 1) * 32 + (lane & 15);
#pragma unroll
      for (int mi = 0; mi < 2; mi++)
#pragma unroll
        for (int ni = 0; ni < 2; ni++)
#pragma unroll
          for (int r = 0; r < 4; r++) {
            int m = row0 + mi * 16 + r;
            int n = col0 + ni * 16;
            int idx = m * 1024 + n;
            float nv = acc[mi][ni][r] + loadf(a.bn, n, isf32);
            float u = ldfc(&a.uf[idx]);
            float h1 = (1.f - u) * nv + u * ldfc(&a.P0f[idx]);
            h1 = fminf(fmaxf(h1, -1e6f), 1e6f);   // insurance clamp
            a.P1f[idx] = h1;
            bf16_t h, mm_, l; split3(h1, h, mm_, l);
            a.P1h[idx] = h; a.P1m[idx] = mm_; a.P1l[idx] = l;
          }
    } else if (t > 0) {
      softmax_rows(bid - 128, t - 1);
    }
    gbar(a.bar);

    // ---- ODE stage lambdas (R1 k_tanh / k_euler epilogues) ----
    auto stage_tanh = [&](const bf16_t* sh, const bf16_t* sm, const bf16_t* sl) {
      const int mt = bid >> 1, nt = bid & 1;
      f32x4 acc[2][2];
      gemm6_dev<false>(AsB, BsB, sh, sm, sl, 1024, nullptr, 0, 0,
                       a.W1Th, a.W1Tm, a.W1Tl, 1024, mt * BM, nt * BN, acc);
      const int row0 = mt * BM + (wid & 1) * 32 + ((lane >> 4) << 2);
      const int col0 = nt * BN + (wid >> 1) * 32 + (lane & 15);
#pragma unroll
      for (int mi = 0; mi < 2; mi++)
#pragma unroll
        for (int ni = 0; ni < 2; ni++)
#pragma unroll
          for (int r = 0; r < 4; r++) {
            int m = row0 + mi * 16 + r;
            int n = col0 + ni * 16;
            float b = (n < 100) ? loadf(a.b1, n, isf32) : 0.f;
            float tv = tanhf(acc[mi][ni][r] + b);
            bf16_t h, mm_, l; split3(tv, h, mm_, l);
            int idx = m * 128 + n;
            a.Th[idx] = h; a.Tm[idx] = mm_; a.Tl[idx] = l;
          }
    };

    auto stage_euler = [&](const float* hprev, float* houtf,
                           bf16_t* hoh, bf16_t* hom, bf16_t* hol, bool wrS) {
      const int mt = bid >> 4, nt = bid & 15;
      f32x4 acc[2][2];
      gemm6_dev<false>(AsB, BsB, a.Th, a.Tm, a.Tl, 128, nullptr, 0, 0,
                       a.W2Th, a.W2Tm, a.W2Tl, 128, mt * BM, nt * BN, acc);
      const int row0 = mt * BM + (wid & 1) * 32 + ((lane >> 4) << 2);
      const int col0 = nt * BN + (wid >> 1) * 32 + (lane & 15);
#pragma unroll
      for (int mi = 0; mi < 2; mi++)
#pragma unroll
        for (int ni = 0; ni < 2; ni++)
#pragma unroll
          for (int r = 0; r < 4; r++) {
            int m = row0 + mi * 16 + r;
            int n = col0 + ni * 16;
            int idx = m * 1024 + n;
            float hv = ldfc(&hprev[idx]) + sdt * (acc[mi][ni][r] + loadf(a.b2, n, isf32));
            hv = fminf(fmaxf(hv, -1e6f), 1e6f);   // insurance clamp
            houtf[idx] = hv;
            bf16_t h, mm_, l; split3(hv, h, mm_, l);
            hoh[idx] = h; hom[idx] = mm_; hol[idx] = l;
            if (wrS)
              a.states[((size_t)t * 512 + m) * 1024 + n] = hv;
          }
    };

    // ======== phase 3: tanh1 (16 tiles) ========
    if (bid < 16) stage_tanh(a.P1h, a.P1m, a.P1l);
    gbar(a.bar);

    // ======== phase 4: euler1 (128 tiles) ========
    if (bid < 128) stage_euler(a.P1f, a.P2f, a.P2h, a.P2m, a.P2l, false);
    gbar(a.bar);

    // ======== phase 5: tanh2 (16 tiles) ========
    if (bid < 16) stage_tanh(a.P2h, a.P2m, a.P2l);
    gbar(a.bar);

    // ======== phase 6: euler2 (128 tiles, writes states + next h) ========
    if (bid < 128) stage_euler(a.P2f, a.P0f, a.P0h, a.P0m, a.P0l, true);
    gbar(a.bar);
  }

  // ======== epilogue: emit(62) + softmax(62) ========
  if (bid < 32) emit_tile();
  gbar(a.bar);
  if (bid < 128) softmax_rows(bid, 62);
}

// ---------------- weight transpose+split into bf16x3 [Npad][Kpad], zero-padded
__global__ void k_transpose_split(const void* __restrict__ src,
                                  bf16_t* __restrict__ dh, bf16_t* __restrict__ dm,
                                  bf16_t* __restrict__ dl,
                                  int K, int N, int Kpad, const int* __restrict__ flg)
{
  const int isf32 = *flg;
  int k = blockIdx.x * 256 + threadIdx.x;
  if (k >= Kpad) return;
  int n = blockIdx.y;  // < Npad
  float v = 0.f;
  if (k < K && n < N) v = loadf(src, k * N + n, isf32);
  bf16_t h, m, l; split3(v, h, m, l);
  size_t idx = (size_t)n * Kpad + k;
  dh[idx] = h; dm[idx] = m; dl[idx] = l;
}

extern "C" void kernel_launch(void* const* d_in, const int* in_sizes, int n_in,
                              void* d_out, int out_size, void* d_ws, size_t ws_size,
                              hipStream_t stream) {
  const void* data = d_in[0];
  const void* ts   = d_in[1];
  const void* Wu   = d_in[2];
  const void* bu   = d_in[3];
  const void* Wr   = d_in[4];
  const void* br   = d_in[5];
  const void* Wn   = d_in[6];
  const void* bn   = d_in[7];
  const void* W1   = d_in[8];
  const void* b1   = d_in[9];
  const void* W2   = d_in[10];
  const void* b2   = d_in[11];
  const void* We   = d_in[12];
  const void* be   = d_in[13];

  float* out_probs  = (float*)d_out;
  float* out_states = (float*)d_out + (size_t)63 * 512 * 256;

  char* p = (char*)d_ws;
  auto carve = [&](size_t bytes) { char* r = p; p += (bytes + 255) & ~255ull; return (void*)r; };
  int*    flg   = (int*)carve(256);
  int*    bar   = (int*)carve(256);
  bf16_t* WurTh = (bf16_t*)carve((size_t)2048 * 1536 * 2);
  bf16_t* WurTm = (bf16_t*)carve((size_t)2048 * 1536 * 2);
  bf16_t* WurTl = (bf16_t*)carve((size_t)2048 * 1536 * 2);
  bf16_t* WnTh  = (bf16_t*)carve((size_t)1024 * 1536 * 2);
  bf16_t* WnTm  = (bf16_t*)carve((size_t)1024 * 1536 * 2);
  bf16_t* WnTl  = (bf16_t*)carve((size_t)1024 * 1536 * 2);
  bf16_t* W1Th  = (bf16_t*)carve((size_t)128 * 1024 * 2);
  bf16_t* W1Tm  = (bf16_t*)carve((size_t)128 * 1024 * 2);
  bf16_t* W1Tl  = (bf16_t*)carve((size_t)128 * 1024 * 2);
  bf16_t* W2Th  = (bf16_t*)carve((size_t)1024 * 128 * 2);
  bf16_t* W2Tm  = (bf16_t*)carve((size_t)1024 * 128 * 2);
  bf16_t* W2Tl  = (bf16_t*)carve((size_t)1024 * 128 * 2);
  bf16_t* WeTh  = (bf16_t*)carve((size_t)256 * 1024 * 2);
  bf16_t* WeTm  = (bf16_t*)carve((size_t)256 * 1024 * 2);
  bf16_t* WeTl  = (bf16_t*)carve((size_t)256 * 1024 * 2);
  float*  P0f = (float*)carve((size_t)512 * 1024 * 4);
  float*  P1f = (float*)carve((size_t)512 * 1024 * 4);
  float*  P2f = (float*)carve((size_t)512 * 1024 * 4);
  bf16_t* P0h = (bf16_t*)carve((size_t)512 * 1024 * 2);
  bf16_t* P0m = (bf16_t*)carve((size_t)512 * 1024 * 2);
  bf16_t* P0l = (bf16_t*)carve((size_t)512 * 1024 * 2);
  bf16_t* P1h = (bf16_t*)carve((size_t)512 * 1024 * 2);
  bf16_t* P1m = (bf16_t*)carve((size_t)512 * 1024 * 2);
  bf16_t* P1l = (bf16_t*)carve((size_t)512 * 1024 * 2);
  bf16_t* P2h = (bf16_t*)carve((size_t)512 * 1024 * 2);
  bf16_t* P2m = (bf16_t*)carve((size_t)512 * 1024 * 2);
  bf16_t* P2l = (bf16_t*)carve((size_t)512 * 1024 * 2);
  bf16_t* HRh = (bf16_t*)carve((size_t)512 * 1024 * 2);
  bf16_t* HRm = (bf16_t*)carve((size_t)512 * 1024 * 2);
  bf16_t* HRl = (bf16_t*)carve((size_t)512 * 1024 * 2);
  float*  uf  = (float*)carve((size_t)512 * 1024 * 4);
  bf16_t* Th  = (bf16_t*)carve((size_t)512 * 128 * 2);
  bf16_t* Tm  = (bf16_t*)carve((size_t)512 * 128 * 2);
  bf16_t* Tl  = (bf16_t*)carve((size_t)512 * 128 * 2);
  float*  lg  = (float*)carve((size_t)512 * 256 * 4);

  // h0 = 0 (f32 and bf16x3 views); barrier state = 0
  (void)hipMemsetAsync(P0f, 0, (size_t)512 * 1024 * 4, stream);
  (void)hipMemsetAsync(P0h, 0, (size_t)512 * 1024 * 2, stream);
  (void)hipMemsetAsync(P0m, 0, (size_t)512 * 1024 * 2, stream);
  (void)hipMemsetAsync(P0l, 0, (size_t)512 * 1024 * 2, stream);
  (void)hipMemsetAsync(bar, 0, 256, stream);

  dim3 b256(256);
  k_probe<<<1, 1, 0, stream>>>((const unsigned int*)ts, flg);

  k_transpose_split<<<dim3(6, 1024), b256, 0, stream>>>(Wu, WurTh, WurTm, WurTl, 1536, 1024, 1536, flg);
  k_transpose_split<<<dim3(6, 1024), b256, 0, stream>>>(Wr, WurTh + (size_t)1024 * 1536,
                                                        WurTm + (size_t)1024 * 1536,
                                                        WurTl + (size_t)1024 * 1536, 1536, 1024, 1536, flg);
  k_transpose_split<<<dim3(6, 1024), b256, 0, stream>>>(Wn, WnTh, WnTm, WnTl, 1536, 1024, 1536, flg);
  k_transpose_split<<<dim3(4, 128),  b256, 0, stream>>>(W1, W1Th, W1Tm, W1Tl, 1024, 100, 1024, flg);
  k_transpose_split<<<dim3(1, 1024), b256, 0, stream>>>(W2, W2Th, W2Tm, W2Tl, 100, 1024, 128, flg);
  k_transpose_split<<<dim3(4, 256),  b256, 0, stream>>>(We, WeTh, WeTm, WeTl, 1024, 256, 1024, flg);

  KArgs ha;
  ha.data = data; ha.ts = ts;
  ha.bu = bu; ha.br = br; ha.bn = bn; ha.b1 = b1; ha.b2 = b2; ha.be = be;
  ha.WurTh = WurTh; ha.WurTm = WurTm; ha.WurTl = WurTl;
  ha.WnTh = WnTh;   ha.WnTm = WnTm;   ha.WnTl = WnTl;
  ha.W1Th = W1Th;   ha.W1Tm = W1Tm;   ha.W1Tl = W1Tl;
  ha.W2Th = W2Th;   ha.W2Tm = W2Tm;   ha.W2Tl = W2Tl;
  ha.WeTh = WeTh;   ha.WeTm = WeTm;   ha.WeTl = WeTl;
  ha.P0f = P0f; ha.P1f = P1f; ha.P2f = P2f; ha.uf = uf; ha.lg = lg;
  ha.P0h = P0h; ha.P0m = P0m; ha.P0l = P0l;
  ha.P1h = P1h; ha.P1m = P1m; ha.P1l = P1l;
  ha.P2h = P2h; ha.P2m = P2m; ha.P2l = P2l;
  ha.HRh = HRh; ha.HRm = HRm; ha.HRl = HRl;
  ha.Th = Th; ha.Tm = Tm; ha.Tl = Tl;
  ha.states = out_states; ha.probs = out_probs;
  ha.flg = flg;
  ha.bar = bar;

  k_mega<<<dim3(NBLK), b256, 0, stream>>>(ha);
}

// Round 8
// 12689.013 us; speedup vs baseline: 1.2875x; 1.2875x over previous
//
#include <hip/hip_runtime.h>

// Decoder ODE-RNN (GRU + Euler-2 ODE + softmax emit). Inputs/outputs FLOAT32.
// f32 GEMM emulated via bf16x3 splitting (6 MFMAs: hh+hm+mh+mm+hl+lh).
// R8 change vs R7 (16.3ms regressed) / R6 (14.1ms best persistent):
//   - REVERT R7 (atomic A-loads, no-acquire barrier): FETCH unchanged proved
//     invalidates were NOT the traffic source. Traffic is structural:
//     activations re-fetched by all 8 XCDs every phase (~105 MB/step), and
//     we run it at latency-limited 477 GB/s with 1 block/CU.
//   - LEVER: 2 blocks/CU -> 2x outstanding L2 misses. 512 blocks, LDS 41.5KB
//     (BN 64->32), __launch_bounds__(256,2). All phases re-tiled for 512
//     tiles (gates 64x32, cand/euler 32x32, tanh 64 tiles, emit 128 rides
//     ph3, softmax rides ph5). Host occupancy query + grid-stride tile loops
//     make any nblk correct (no deadlock).
// Per-output-element K-order identical to R1/R6 -> bit-identical (absmax 1.0).

typedef __bf16 bf16_t;
typedef __bf16 bf16x8 __attribute__((ext_vector_type(8)));
typedef float  f32x4  __attribute__((ext_vector_type(4)));

#define LDT 72    // padded LDS row stride (elems)

__device__ __forceinline__ float sigmoidf_(float x) { return 1.f / (1.f + expf(-x)); }

__device__ __forceinline__ void split3(float v, bf16_t& h, bf16_t& m, bf16_t& l) {
  h = (bf16_t)v; float r1 = v - (float)h;
  m = (bf16_t)r1; float r2 = r1 - (float)m;
  l = (bf16_t)r2;
}

#define CHAIN6(c, ah, am, al, bh, bm, bl) \
  c = __builtin_amdgcn_mfma_f32_16x16x32_bf16(ah, bh, c, 0, 0, 0); \
  c = __builtin_amdgcn_mfma_f32_16x16x32_bf16(ah, bm, c, 0, 0, 0); \
  c = __builtin_amdgcn_mfma_f32_16x16x32_bf16(am, bh, c, 0, 0, 0); \
  c = __builtin_amdgcn_mfma_f32_16x16x32_bf16(am, bm, c, 0, 0, 0); \
  c = __builtin_amdgcn_mfma_f32_16x16x32_bf16(ah, bl, c, 0, 0, 0); \
  c = __builtin_amdgcn_mfma_f32_16x16x32_bf16(al, bh, c, 0, 0, 0);

// flag-aware loads from HARNESS inputs (f32 vs bf16 decided at runtime)
__device__ __forceinline__ void loadf8(const void* p, size_t idx, int isf32, float out[8]) {
  if (isf32) {
    const float* q = (const float*)p + idx;
    f32x4 a = *(const f32x4*)q;
    f32x4 b = *(const f32x4*)(q + 4);
    out[0]=a[0]; out[1]=a[1]; out[2]=a[2]; out[3]=a[3];
    out[4]=b[0]; out[5]=b[1]; out[6]=b[2]; out[7]=b[3];
  } else {
    bf16x8 v = *(const bf16x8*)((const bf16_t*)p + idx);
#pragma unroll
    for (int i = 0; i < 8; i++) out[i] = (float)v[i];
  }
}
__device__ __forceinline__ float loadf(const void* p, int idx, int isf32) {
  return isf32 ? ((const float*)p)[idx] : (float)((const bf16_t*)p)[idx];
}

__global__ void k_probe(const unsigned int* ts_raw, int* flag) {
  *flag = (ts_raw[0] == 0u) ? 1 : 0;   // 1 = f32 inputs, 0 = bf16 inputs
}

// ---------------- grid-wide barrier (R6-proven: relaxed spin + single acquire)
__device__ __forceinline__ void gbar(int* bar, int nblk) {
  __syncthreads();
  if (threadIdx.x == 0) {
    int g = __hip_atomic_load(bar + 32, __ATOMIC_RELAXED, __HIP_MEMORY_SCOPE_AGENT);
    int old = __hip_atomic_fetch_add(bar, 1, __ATOMIC_ACQ_REL, __HIP_MEMORY_SCOPE_AGENT);
    if (old == nblk - 1) {
      __hip_atomic_store(bar, 0, __ATOMIC_RELAXED, __HIP_MEMORY_SCOPE_AGENT);
      __hip_atomic_fetch_add(bar + 32, 1, __ATOMIC_RELEASE, __HIP_MEMORY_SCOPE_AGENT);
    } else {
      int polls = 0;
      for (;;) {
        if (__hip_atomic_load(bar + 32, __ATOMIC_RELAXED, __HIP_MEMORY_SCOPE_AGENT) != g)
          break;
        __builtin_amdgcn_s_sleep(8);
        if (((++polls) & 255) == 0) {
          if (__hip_atomic_load(bar + 32, __ATOMIC_ACQUIRE, __HIP_MEMORY_SCOPE_AGENT) != g)
            break;
        }
      }
      (void)__hip_atomic_load(bar + 32, __ATOMIC_ACQUIRE, __HIP_MEMORY_SCOPE_AGENT);
    }
  }
  __syncthreads();
}

// ---------------- templated split-precision GEMM core.
// Block tile = (RM*32) x (RN*32); 4 warps in 2x2; warp tile (RM*16)x(RN*16).
// Per-output-element K accumulation order identical to the R1 core.
template<int RM, int RN, bool CATX>
__device__ __forceinline__ void gemm6t(
    bf16_t* __restrict__ As, bf16_t* __restrict__ Bs,
    const bf16_t* __restrict__ Ah, const bf16_t* __restrict__ Am, const bf16_t* __restrict__ Al,
    int lda,
    const void* __restrict__ X, int isf32, int t,
    const bf16_t* __restrict__ Bh, const bf16_t* __restrict__ Bm, const bf16_t* __restrict__ Bl,
    int K, int mBase, int nBase,
    f32x4 (&acc)[RM][RN])
{
  constexpr int BMv = RM * 32;
  constexpr int BNv = RN * 32;
  constexpr int CA  = RM * 8;       // A elems staged per thread (per 64-col tile)
  constexpr int CB  = RN * 8;
  constexpr int TPRA = 64 / CA;     // threads per A row
  constexpr int TPRB = 64 / CB;

  const int tid   = threadIdx.x;
  const int srowA = tid / TPRA;
  const int scA   = (tid % TPRA) * CA;
  const int srowB = tid / TPRB;
  const int scB   = (tid % TPRB) * CB;
  const int arow  = mBase + srowA;
  const int brow  = nBase + srowB;

  const int lane = tid & 63;
  const int wid  = tid >> 6;
  const int wm   = (wid & 1) * (RM * 16);
  const int wn   = (wid >> 1) * (RN * 16);
  const int q8   = (lane >> 4) << 3;
  const int l16  = lane & 15;

  f32x4 z = {0.f, 0.f, 0.f, 0.f};
#pragma unroll
  for (int i = 0; i < RM; i++)
#pragma unroll
    for (int j = 0; j < RN; j++) acc[i][j] = z;

  const bf16_t* Ap[3] = {Ah, Am, Al};
  const bf16_t* Bp[3] = {Bh, Bm, Bl};
  bf16x8 pA[3][RM], pB[3][RN];

  auto loadA = [&](int k0) {
    int gk = k0 + scA;
    if (CATX && gk >= 1024) {
      size_t off = (size_t)arow * 32768 + (size_t)t * 512 + (size_t)(gk - 1024);
      float v[CA];
#pragma unroll
      for (int c = 0; c < RM; c++) loadf8(X, off + c * 8, isf32, v + c * 8);
#pragma unroll
      for (int c = 0; c < RM; c++)
#pragma unroll
        for (int j = 0; j < 8; j++) {
          bf16_t h, m, l; split3(v[c * 8 + j], h, m, l);
          pA[0][c][j] = h; pA[1][c][j] = m; pA[2][c][j] = l;
        }
    } else {
      size_t off = (size_t)arow * lda + gk;
#pragma unroll
      for (int p = 0; p < 3; p++)
#pragma unroll
        for (int c = 0; c < RM; c++)
          pA[p][c] = *(const bf16x8*)(Ap[p] + off + c * 8);
    }
  };
  auto loadB = [&](int k0) {
    size_t off = (size_t)brow * K + k0 + scB;
#pragma unroll
    for (int p = 0; p < 3; p++)
#pragma unroll
      for (int c = 0; c < RN; c++)
        pB[p][c] = *(const bf16x8*)(Bp[p] + off + c * 8);
  };

  loadA(0); loadB(0);

  for (int k0 = 0; k0 < K; k0 += 64) {
#pragma unroll
    for (int p = 0; p < 3; p++) {
#pragma unroll
      for (int c = 0; c < RM; c++)
        *(bf16x8*)&As[p * (BMv * LDT) + srowA * LDT + scA + c * 8] = pA[p][c];
#pragma unroll
      for (int c = 0; c < RN; c++)
        *(bf16x8*)&Bs[p * (BNv * LDT) + srowB * LDT + scB + c * 8] = pB[p][c];
    }
    __syncthreads();

    if (k0 + 64 < K) { loadA(k0 + 64); loadB(k0 + 64); }

#pragma unroll
    for (int kk = 0; kk < 64; kk += 32) {
      bf16x8 a[RM][3], b[RN][3];
#pragma unroll
      for (int p = 0; p < 3; p++) {
#pragma unroll
        for (int mi = 0; mi < RM; mi++)
          a[mi][p] = *(const bf16x8*)&As[p * (BMv * LDT) + (wm + mi * 16 + l16) * LDT + kk + q8];
#pragma unroll
        for (int ni = 0; ni < RN; ni++)
          b[ni][p] = *(const bf16x8*)&Bs[p * (BNv * LDT) + (wn + ni * 16 + l16) * LDT + kk + q8];
      }
#pragma unroll
      for (int mi = 0; mi < RM; mi++)
#pragma unroll
        for (int ni = 0; ni < RN; ni++) {
          f32x4 c = acc[mi][ni];
          CHAIN6(c, a[mi][0], a[mi][1], a[mi][2], b[ni][0], b[ni][1], b[ni][2]);
          acc[mi][ni] = c;
        }
    }
    __syncthreads();
  }
}

// ---------------- args for the persistent mega-kernel
struct KArgs {
  const void* data; const void* ts;
  const void* bu; const void* br; const void* bn;
  const void* b1; const void* b2; const void* be;
  const bf16_t *WurTh, *WurTm, *WurTl;
  const bf16_t *WnTh,  *WnTm,  *WnTl;
  const bf16_t *W1Th,  *W1Tm,  *W1Tl;
  const bf16_t *W2Th,  *W2Tm,  *W2Tl;
  const bf16_t *WeTh,  *WeTm,  *WeTl;
  float *P0f, *P1f, *P2f, *uf, *lg;
  bf16_t *P0h, *P0m, *P0l;
  bf16_t *P1h, *P1m, *P1l;
  bf16_t *P2h, *P2m, *P2l;
  bf16_t *HRh, *HRm, *HRl;
  bf16_t *Th,  *Tm,  *Tl;
  float *states, *probs;
  const int* flg;
  int* bar;
};

// ---------------- persistent kernel: entire 63-step loop.
// nblk blocks (512 at 2/CU expected), grid-stride tile loops per phase.
__global__ __launch_bounds__(256, 2) void k_mega(KArgs a, int nblk)
{
  __shared__ __align__(16) bf16_t As[3 * 64 * LDT];   // 27648 B (max BM=64)
  __shared__ __align__(16) bf16_t Bs[3 * 32 * LDT];   // 13824 B (BN=32)

  const int bid  = blockIdx.x;
  const int tid  = threadIdx.x;
  const int lane = tid & 63;
  const int wid  = tid >> 6;
  const int l16  = lane & 15;
  const int isf32 = *a.flg;

  // ---- emit tile ti in [0,128): 32x32, logits = h @ We + be
  auto emit_tile = [&](int ti) {
    const int mt = ti >> 3, nt = ti & 7;
    f32x4 acc[1][1];
    gemm6t<1, 1, false>(As, Bs, a.P0h, a.P0m, a.P0l, 1024, nullptr, 0, 0,
                        a.WeTh, a.WeTm, a.WeTl, 1024, mt * 32, nt * 32, acc);
    const int row0 = mt * 32 + (wid & 1) * 16 + ((lane >> 4) << 2);
    const int col0 = nt * 32 + (wid >> 1) * 16 + l16;
#pragma unroll
    for (int r = 0; r < 4; r++) {
      int m = row0 + r;
      a.lg[m * 256 + col0] = acc[0][0][r] + loadf(a.be, col0, isf32);
    }
  };

  // ---- softmax: 4 rows per sb in [0,128)
  auto softmax_rows = [&](int sb, int t) {
    float* red = (float*)As;   // block-local LDS scratch
#pragma unroll
    for (int rr = 0; rr < 4; ++rr) {
      int m = sb * 4 + rr;
      float v = a.lg[m * 256 + tid];
      red[tid] = v;
      __syncthreads();
      for (int s = 128; s > 0; s >>= 1) {
        if (tid < s) red[tid] = fmaxf(red[tid], red[tid + s]);
        __syncthreads();
      }
      float mx = red[0];
      __syncthreads();
      float e = expf(v - mx);
      red[tid] = e;
      __syncthreads();
      for (int s = 128; s > 0; s >>= 1) {
        if (tid < s) red[tid] += red[tid + s];
        __syncthreads();
      }
      a.probs[((size_t)t * 512 + m) * 256 + tid] = e / red[0];
      __syncthreads();
    }
  };

  // ---- tanh tile ti in [0,64): 32x32, T = tanh(h @ W1 + b1)
  auto tanh_tile = [&](int ti, const bf16_t* sh, const bf16_t* sm, const bf16_t* sl) {
    const int mt = ti >> 2, nt = ti & 3;
    f32x4 acc[1][1];
    gemm6t<1, 1, false>(As, Bs, sh, sm, sl, 1024, nullptr, 0, 0,
                        a.W1Th, a.W1Tm, a.W1Tl, 1024, mt * 32, nt * 32, acc);
    const int row0 = mt * 32 + (wid & 1) * 16 + ((lane >> 4) << 2);
    const int col0 = nt * 32 + (wid >> 1) * 16 + l16;
    float b = (col0 < 100) ? loadf(a.b1, col0, isf32) : 0.f;
#pragma unroll
    for (int r = 0; r < 4; r++) {
      int m = row0 + r;
      float tv = tanhf(acc[0][0][r] + b);
      bf16_t h, mm_, l; split3(tv, h, mm_, l);
      int idx = m * 128 + col0;
      a.Th[idx] = h; a.Tm[idx] = mm_; a.Tl[idx] = l;
    }
  };

  // ---- euler tile ti in [0,512): 32x32, h_out = h_prev + sdt*(T @ W2 + b2)
  auto euler_tile = [&](int ti, float sdt, const float* hprev, float* houtf,
                        bf16_t* hoh, bf16_t* hom, bf16_t* hol, bool wrS, int t) {
    const int mt = ti >> 5, nt = ti & 31;
    f32x4 acc[1][1];
    gemm6t<1, 1, false>(As, Bs, a.Th, a.Tm, a.Tl, 128, nullptr, 0, 0,
                        a.W2Th, a.W2Tm, a.W2Tl, 128, mt * 32, nt * 32, acc);
    const int row0 = mt * 32 + (wid & 1) * 16 + ((lane >> 4) << 2);
    const int col0 = nt * 32 + (wid >> 1) * 16 + l16;
    float b = loadf(a.b2, col0, isf32);
#pragma unroll
    for (int r = 0; r < 4; r++) {
      int m = row0 + r;
      int idx = m * 1024 + col0;
      float hv = hprev[idx] + sdt * (acc[0][0][r] + b);
      hv = fminf(fmaxf(hv, -1e6f), 1e6f);   // insurance clamp
      houtf[idx] = hv;
      bf16_t h, mm_, l; split3(hv, h, mm_, l);
      hoh[idx] = h; hom[idx] = mm_; hol[idx] = l;
      if (wrS)
        a.states[((size_t)t * 512 + m) * 1024 + col0] = hv;
    }
  };

  for (int t = 0; t < 63; ++t) {
    const float sdt = 0.5f * (loadf(a.ts, t + 1, isf32) - loadf(a.ts, t, isf32));

    // ======== phase 1: gates (512 tiles, 64x32) ========
    for (int tile = bid; tile < 512; tile += nblk) {
      const int mt = tile >> 6, nt = tile & 63;
      f32x4 acc[2][1];
      gemm6t<2, 1, true>(As, Bs, a.P0h, a.P0m, a.P0l, 1024, a.data, isf32, t,
                         a.WurTh, a.WurTm, a.WurTl, 1536, mt * 64, nt * 32, acc);
      const int row0 = mt * 64 + (wid & 1) * 32 + ((lane >> 4) << 2);
      const int col0 = nt * 32 + (wid >> 1) * 16 + l16;
#pragma unroll
      for (int mi = 0; mi < 2; mi++)
#pragma unroll
        for (int r = 0; r < 4; r++) {
          int m = row0 + mi * 16 + r;
          int n = col0;
          float v = acc[mi][0][r];
          if (n < 1024) {
            a.uf[m * 1024 + n] = sigmoidf_(v + loadf(a.bu, n, isf32));
          } else {
            int nn = n - 1024;
            float rr = sigmoidf_(v + loadf(a.br, nn, isf32));
            float hv = a.P0f[m * 1024 + nn] * rr;
            bf16_t h, mm_, l; split3(hv, h, mm_, l);
            int idx = m * 1024 + nn;
            a.HRh[idx] = h; a.HRm[idx] = mm_; a.HRl[idx] = l;
          }
        }
    }
    gbar(a.bar, nblk);

    // ======== phase 2: cand (512 tiles, 32x32) ========
    for (int tile = bid; tile < 512; tile += nblk) {
      const int mt = tile >> 5, nt = tile & 31;
      f32x4 acc[1][1];
      gemm6t<1, 1, true>(As, Bs, a.HRh, a.HRm, a.HRl, 1024, a.data, isf32, t,
                         a.WnTh, a.WnTm, a.WnTl, 1536, mt * 32, nt * 32, acc);
      const int row0 = mt * 32 + (wid & 1) * 16 + ((lane >> 4) << 2);
      const int col0 = nt * 32 + (wid >> 1) * 16 + l16;
#pragma unroll
      for (int r = 0; r < 4; r++) {
        int m = row0 + r;
        int idx = m * 1024 + col0;
        float nv = acc[0][0][r] + loadf(a.bn, col0, isf32);
        float u = a.uf[idx];
        float h1 = (1.f - u) * nv + u * a.P0f[idx];
        h1 = fminf(fmaxf(h1, -1e6f), 1e6f);   // insurance clamp
        a.P1f[idx] = h1;
        bf16_t h, mm_, l; split3(h1, h, mm_, l);
        a.P1h[idx] = h; a.P1m[idx] = mm_; a.P1l[idx] = l;
      }
    }
    gbar(a.bar, nblk);

    // ======== phase 3: tanh1 (64 tiles) + emit(t-1) (blocks 64..191) ========
    for (int tile = bid; tile < 64; tile += nblk)
      tanh_tile(tile, a.P1h, a.P1m, a.P1l);
    if (t > 0 && bid >= 64 && bid < 192) emit_tile(bid - 64);
    gbar(a.bar, nblk);

    // ======== phase 4: euler1 (512 tiles) ========
    for (int tile = bid; tile < 512; tile += nblk)
      euler_tile(tile, sdt, a.P1f, a.P2f, a.P2h, a.P2m, a.P2l, false, t);
    gbar(a.bar, nblk);

    // ======== phase 5: tanh2 (64 tiles) + softmax(t-1) (blocks 64..191) ====
    for (int tile = bid; tile < 64; tile += nblk)
      tanh_tile(tile, a.P2h, a.P2m, a.P2l);
    if (t > 0 && bid >= 64 && bid < 192) softmax_rows(bid - 64, t - 1);
    gbar(a.bar, nblk);

    // ======== phase 6: euler2 (512 tiles, writes states + next h) ========
    for (int tile = bid; tile < 512; tile += nblk)
      euler_tile(tile, sdt, a.P2f, a.P0f, a.P0h, a.P0m, a.P0l, true, t);
    gbar(a.bar, nblk);
  }

  // ======== epilogue: emit(62) + softmax(62) ========
  if (bid >= 64 && bid < 192) emit_tile(bid - 64);
  gbar(a.bar, nblk);
  if (bid >= 64 && bid < 192) softmax_rows(bid - 64, 62);
}

// ---------------- weight transpose+split into bf16x3 [Npad][Kpad], zero-padded
__global__ void k_transpose_split(const void* __restrict__ src,
                                  bf16_t* __restrict__ dh, bf16_t* __restrict__ dm,
                                  bf16_t* __restrict__ dl,
                                  int K, int N, int Kpad, const int* __restrict__ flg)
{
  const int isf32 = *flg;
  int k = blockIdx.x * 256 + threadIdx.x;
  if (k >= Kpad) return;
  int n = blockIdx.y;  // < Npad
  float v = 0.f;
  if (k < K && n < N) v = loadf(src, k * N + n, isf32);
  bf16_t h, m, l; split3(v, h, m, l);
  size_t idx = (size_t)n * Kpad + k;
  dh[idx] = h; dm[idx] = m; dl[idx] = l;
}

extern "C" void kernel_launch(void* const* d_in, const int* in_sizes, int n_in,
                              void* d_out, int out_size, void* d_ws, size_t ws_size,
                              hipStream_t stream) {
  const void* data = d_in[0];
  const void* ts   = d_in[1];
  const void* Wu   = d_in[2];
  const void* bu   = d_in[3];
  const void* Wr   = d_in[4];
  const void* br   = d_in[5];
  const void* Wn   = d_in[6];
  const void* bn   = d_in[7];
  const void* W1   = d_in[8];
  const void* b1   = d_in[9];
  const void* W2   = d_in[10];
  const void* b2   = d_in[11];
  const void* We   = d_in[12];
  const void* be   = d_in[13];

  float* out_probs  = (float*)d_out;
  float* out_states = (float*)d_out + (size_t)63 * 512 * 256;

  char* p = (char*)d_ws;
  auto carve = [&](size_t bytes) { char* r = p; p += (bytes + 255) & ~255ull; return (void*)r; };
  int*    flg   = (int*)carve(256);
  int*    bar   = (int*)carve(256);
  bf16_t* WurTh = (bf16_t*)carve((size_t)2048 * 1536 * 2);
  bf16_t* WurTm = (bf16_t*)carve((size_t)2048 * 1536 * 2);
  bf16_t* WurTl = (bf16_t*)carve((size_t)2048 * 1536 * 2);
  bf16_t* WnTh  = (bf16_t*)carve((size_t)1024 * 1536 * 2);
  bf16_t* WnTm  = (bf16_t*)carve((size_t)1024 * 1536 * 2);
  bf16_t* WnTl  = (bf16_t*)carve((size_t)1024 * 1536 * 2);
  bf16_t* W1Th  = (bf16_t*)carve((size_t)128 * 1024 * 2);
  bf16_t* W1Tm  = (bf16_t*)carve((size_t)128 * 1024 * 2);
  bf16_t* W1Tl  = (bf16_t*)carve((size_t)128 * 1024 * 2);
  bf16_t* W2Th  = (bf16_t*)carve((size_t)1024 * 128 * 2);
  bf16_t* W2Tm  = (bf16_t*)carve((size_t)1024 * 128 * 2);
  bf16_t* W2Tl  = (bf16_t*)carve((size_t)1024 * 128 * 2);
  bf16_t* WeTh  = (bf16_t*)carve((size_t)256 * 1024 * 2);
  bf16_t* WeTm  = (bf16_t*)carve((size_t)256 * 1024 * 2);
  bf16_t* WeTl  = (bf16_t*)carve((size_t)256 * 1024 * 2);
  float*  P0f = (float*)carve((size_t)512 * 1024 * 4);
  float*  P1f = (float*)carve((size_t)512 * 1024 * 4);
  float*  P2f = (float*)carve((size_t)512 * 1024 * 4);
  bf16_t* P0h = (bf16_t*)carve((size_t)512 * 1024 * 2);
  bf16_t* P0m = (bf16_t*)carve((size_t)512 * 1024 * 2);
  bf16_t* P0l = (bf16_t*)carve((size_t)512 * 1024 * 2);
  bf16_t* P1h = (bf16_t*)carve((size_t)512 * 1024 * 2);
  bf16_t* P1m = (bf16_t*)carve((size_t)512 * 1024 * 2);
  bf16_t* P1l = (bf16_t*)carve((size_t)512 * 1024 * 2);
  bf16_t* P2h = (bf16_t*)carve((size_t)512 * 1024 * 2);
  bf16_t* P2m = (bf16_t*)carve((size_t)512 * 1024 * 2);
  bf16_t* P2l = (bf16_t*)carve((size_t)512 * 1024 * 2);
  bf16_t* HRh = (bf16_t*)carve((size_t)512 * 1024 * 2);
  bf16_t* HRm = (bf16_t*)carve((size_t)512 * 1024 * 2);
  bf16_t* HRl = (bf16_t*)carve((size_t)512 * 1024 * 2);
  float*  uf  = (float*)carve((size_t)512 * 1024 * 4);
  bf16_t* Th  = (bf16_t*)carve((size_t)512 * 128 * 2);
  bf16_t* Tm  = (bf16_t*)carve((size_t)512 * 128 * 2);
  bf16_t* Tl  = (bf16_t*)carve((size_t)512 * 128 * 2);
  float*  lg  = (float*)carve((size_t)512 * 256 * 4);

  // h0 = 0 (f32 and bf16x3 views); barrier state = 0
  (void)hipMemsetAsync(P0f, 0, (size_t)512 * 1024 * 4, stream);
  (void)hipMemsetAsync(P0h, 0, (size_t)512 * 1024 * 2, stream);
  (void)hipMemsetAsync(P0m, 0, (size_t)512 * 1024 * 2, stream);
  (void)hipMemsetAsync(P0l, 0, (size_t)512 * 1024 * 2, stream);
  (void)hipMemsetAsync(bar, 0, 256, stream);

  dim3 b256(256);
  k_probe<<<1, 1, 0, stream>>>((const unsigned int*)ts, flg);

  k_transpose_split<<<dim3(6, 1024), b256, 0, stream>>>(Wu, WurTh, WurTm, WurTl, 1536, 1024, 1536, flg);
  k_transpose_split<<<dim3(6, 1024), b256, 0, stream>>>(Wr, WurTh + (size_t)1024 * 1536,
                                                        WurTm + (size_t)1024 * 1536,
                                                        WurTl + (size_t)1024 * 1536, 1536, 1024, 1536, flg);
  k_transpose_split<<<dim3(6, 1024), b256, 0, stream>>>(Wn, WnTh, WnTm, WnTl, 1536, 1024, 1536, flg);
  k_transpose_split<<<dim3(4, 128),  b256, 0, stream>>>(W1, W1Th, W1Tm, W1Tl, 1024, 100, 1024, flg);
  k_transpose_split<<<dim3(1, 1024), b256, 0, stream>>>(W2, W2Th, W2Tm, W2Tl, 100, 1024, 128, flg);
  k_transpose_split<<<dim3(4, 256),  b256, 0, stream>>>(We, WeTh, WeTm, WeTl, 1024, 256, 1024, flg);

  KArgs ha;
  ha.data = data; ha.ts = ts;
  ha.bu = bu; ha.br = br; ha.bn = bn; ha.b1 = b1; ha.b2 = b2; ha.be = be;
  ha.WurTh = WurTh; ha.WurTm = WurTm; ha.WurTl = WurTl;
  ha.WnTh = WnTh;   ha.WnTm = WnTm;   ha.WnTl = WnTl;
  ha.W1Th = W1Th;   ha.W1Tm = W1Tm;   ha.W1Tl = W1Tl;
  ha.W2Th = W2Th;   ha.W2Tm = W2Tm;   ha.W2Tl = W2Tl;
  ha.WeTh = WeTh;   ha.WeTm = WeTm;   ha.WeTl = WeTl;
  ha.P0f = P0f; ha.P1f = P1f; ha.P2f = P2f; ha.uf = uf; ha.lg = lg;
  ha.P0h = P0h; ha.P0m = P0m; ha.P0l = P0l;
  ha.P1h = P1h; ha.P1m = P1m; ha.P1l = P1l;
  ha.P2h = P2h; ha.P2m = P2m; ha.P2l = P2l;
  ha.HRh = HRh; ha.HRm = HRm; ha.HRl = HRl;
  ha.Th = Th; ha.Tm = Tm; ha.Tl = Tl;
  ha.states = out_states; ha.probs = out_probs;
  ha.flg = flg;
  ha.bar = bar;

  // residency-guarded persistent launch: 512 blocks iff 2 blocks/CU fit
  int occ = 0;
  (void)hipOccupancyMaxActiveBlocksPerMultiprocessor(&occ, k_mega, 256, 0);
  int nblk = (occ >= 2) ? 512 : 256;

  k_mega<<<dim3(nblk), b256, 0, stream>>>(ha, nblk);
}